// Round 1
// baseline (134.415 us; speedup 1.0000x reference)
//
#include <hip/hip_runtime.h>
#include <math.h>

#define H 2400
#define W 2400
#define SX 30
#define SY 30
#define NBX 80
#define NBY 80
#define NBLK (NBX * NBY)
#define GCOEF 0.5f
#define PI_F 3.14159265358979323846f

// One wave64 = two horizontally adjacent 30x30 blocks, column-per-lane sweep.
// lanes 0..31  -> block A, columns gj0-1 .. gj0+30 (incl. halo cols)
// lanes 32..63 -> block B, columns gj0+29 .. gj0+60 (incl. halo cols)
// (2-col overlap makes each 32-lane half self-contained, so xor-butterfly
//  offsets 16..1 reduce both blocks at once.)
// Sweep rows top->bottom carrying 3 rows of horizontal mask-sums in regs:
// zero LDS, zero __syncthreads, 1 coalesced global load per row per lane.
__global__ __launch_bounds__(256) void block_stats(
    const float* __restrict__ chm,
    const float* __restrict__ th,
    const float* __restrict__ favd,
    const float* __restrict__ sza,
    float* __restrict__ sums)          // [NBLK][8]
{
    const int tid   = threadIdx.x;
    const int wv    = tid >> 6;          // wave in workgroup: 4 pairs/WG
    const int lane  = tid & 63;
    const int laneq = lane & 31;
    const int half  = lane >> 5;         // 0 = block A, 1 = block B

    const int bx   = blockIdx.x / 10;            // block-row 0..79
    const int pair = (blockIdx.x % 10) * 4 + wv; // pair of block-cols 0..39
    const int gi0  = bx * SX;
    const int gj0  = pair * (2 * SY);
    const int gj   = gj0 - 1 + laneq + half * SY;   // this lane's column
    const bool gj_ok  = (gj >= 0) && (gj < W);
    const bool active = (laneq >= 1) && (laneq <= 30);  // interior column lanes
    const int blk  = bx * NBY + pair * 2 + half;

    const float th_b   = th[blk];
    const float a      = -GCOEF * favd[blk];
    const float mu     = fmaxf(cosf(sza[blk] * (PI_F / 180.0f)), 1e-3f);
    const float inv_mu = 1.0f / mu;

    const float* colp = chm + gj;   // column base; row r at colp[gi*W]

    // --- prologue: rows gi0-1 (halo) and gi0 ---
    float rsU, rsC, rsD, bC, vC;
    {
        int gi = gi0 - 1;
        float v = (gi >= 0 && gj_ok) ? colp[gi * W] : 0.0f;
        float b = (v > 0.0f) ? 1.0f : 0.0f;
        rsU = __shfl_up(b, 1, 32) + b + __shfl_down(b, 1, 32);
    }
    {
        float v = gj_ok ? colp[gi0 * W] : 0.0f;
        bC = (v > 0.0f) ? 1.0f : 0.0f;
        vC = v;
        rsC = __shfl_up(bC, 1, 32) + bC + __shfl_down(bC, 1, 32);
    }

    float s_mask = 0.f, s_edge = 0.f, s_gs = 0.f, s_gv = 0.f;
    float s_chm = 0.f, s_egs = 0.f, s_mgv = 0.f;
    float vmax = -INFINITY;

    for (int r = 0; r < SX; ++r) {
        // load the row BELOW the one being processed
        int giD = gi0 + r + 1;
        float v = (giD < H && gj_ok) ? colp[giD * W] : 0.0f;
        float b = (v > 0.0f) ? 1.0f : 0.0f;
        rsD = __shfl_up(b, 1, 32) + b + __shfl_down(b, 1, 32);

        // process row gi0+r (values in vC/bC, hsum in rsU/rsC/rsD)
        int gi = gi0 + r;
        float ns = rsU + rsC + rsD - bC;                 // 8-neighbor mask count
        bool interior = (gi >= 1) & (gi <= H - 2) & (gj >= 1) & (gj <= W - 2);
        float edge = (bC != 0.0f && interior && ns <= 6.0f) ? 1.0f : 0.0f;

        float crown = fmaxf(vC - th_b, 0.0f);
        float ac = a * crown;
        float gv = __expf(ac);
        float gs = __expf(ac * inv_mu);

        if (active) {
            s_mask += bC;
            s_edge += edge;
            s_gs   += gs;
            s_gv   += gv;
            s_chm  += vC;
            s_egs  += edge * gs;
            s_mgv  += bC * gv;
            vmax = fmaxf(vmax, vC);
        }

        rsU = rsC; rsC = rsD; vC = v; bC = b;
    }

    // xor-butterfly: offsets <32 keep the two 32-lane halves independent,
    // reducing block A and block B simultaneously. Halo lanes hold 0 / -inf.
    for (int off = 16; off >= 1; off >>= 1) {
        s_mask += __shfl_xor(s_mask, off, 64);
        s_edge += __shfl_xor(s_edge, off, 64);
        s_gs   += __shfl_xor(s_gs,   off, 64);
        s_gv   += __shfl_xor(s_gv,   off, 64);
        s_chm  += __shfl_xor(s_chm,  off, 64);
        s_egs  += __shfl_xor(s_egs,  off, 64);
        s_mgv  += __shfl_xor(s_mgv,  off, 64);
        vmax = fmaxf(vmax, __shfl_xor(vmax, off, 64));
    }
    if (laneq == 0) {
        float4* o = (float4*)&sums[blk * 8];
        o[0] = make_float4(s_mask, s_edge, s_gs, s_gv);
        o[1] = make_float4(s_chm, s_egs, s_mgv, vmax);
    }
}

// 25 blocks x 256 threads: each block redundantly max-reduces the 6400
// per-block maxes (25 KB, L2-hot), then each thread emits exactly one BRF.
__global__ __launch_bounds__(256) void finalize_all(
    const float* __restrict__ sums,    // [NBLK][8]
    const float* __restrict__ saa,
    const float* __restrict__ rl,
    const float* __restrict__ tl,
    const float* __restrict__ rs,
    const float* __restrict__ belta,
    float* __restrict__ out)
{
    __shared__ float smax[4];
    const int tid = threadIdx.x;

    float m = -INFINITY;
    for (int i = tid; i < NBLK; i += 256) m = fmaxf(m, sums[i * 8 + 7]);
    for (int off = 32; off >= 1; off >>= 1) m = fmaxf(m, __shfl_xor(m, off, 64));
    if ((tid & 63) == 0) smax[tid >> 6] = m;
    __syncthreads();
    const float gmax = fmaxf(fmaxf(smax[0], smax[1]), fmaxf(smax[2], smax[3]));
    const float inv_max = 1.0f / gmax;
    const float invN = 1.0f / 900.0f;

    const int b = blockIdx.x * 256 + tid;   // 25*256 == NBLK exactly

    float4 lo = *(const float4*)&sums[b * 8];
    float4 hi = *(const float4*)&sums[b * 8 + 4];
    float s_mask = lo.x;
    float s_edge = lo.y;
    float te0  = lo.z * invN;     // mean gap_sun
    float te1  = lo.w * invN;     // mean gap_view
    float s_chm = hi.x;
    float te11 = hi.y * invN;     // mean edge*gap_sun
    float te12 = hi.z * invN;     // mean mask*gap_view

    float te10 = s_chm * invN * inv_max;  // mean rel_h
    float te7  = s_edge * invN;           // mean edge
    float f_gap = ((900.0f - s_mask) + 0.5f * s_edge) * invN;

    float Pgs   = te0;
    float Pboth = te0 * te1;
    float Kg = f_gap * Pgs;
    float Kz = f_gap * (1.0f - Pgs);
    float Kc = (1.0f - f_gap) * Pboth;
    float Kt = fmaxf((1.0f - f_gap) - Kc, 0.0f);
    float hot = 1.0f + 0.1f * cosf(saa[b] * (PI_F / 180.0f));

    float brf = (rl[b] * Kc + tl[b] * belta[b] * Kt + rs[b] * Kg
               + rs[b] * belta[b] * Kz + rl[b] * te7 * te10
               + tl[b] * (1.0f - belta[b]) * te11
               + rs[b] * te12 * f_gap) * hot;

    out[0 * NBLK + b] = brf;
    out[1 * NBLK + b] = brf;
    out[2 * NBLK + b] = brf;
    out[3 * NBLK + b] = brf;
}

extern "C" void kernel_launch(void* const* d_in, const int* in_sizes, int n_in,
                              void* d_out, int out_size, void* d_ws, size_t ws_size,
                              hipStream_t stream) {
    const float* chm   = (const float*)d_in[0];
    // d_in[1] = PATH1, d_in[2] = PATH2 — dead code in the reference's output
    const float* th    = (const float*)d_in[3];
    const float* favd  = (const float*)d_in[4];
    const float* sza   = (const float*)d_in[5];
    const float* saa   = (const float*)d_in[6];
    const float* rl    = (const float*)d_in[7];
    const float* tl    = (const float*)d_in[8];
    const float* rs    = (const float*)d_in[9];
    const float* belta = (const float*)d_in[10];
    float* out = (float*)d_out;

    float* sums = (float*)d_ws;   // [NBLK][8] floats

    block_stats<<<NBX * 10, 256, 0, stream>>>(chm, th, favd, sza, sums);
    finalize_all<<<NBLK / 256, 256, 0, stream>>>(sums, saa, rl, tl, rs, belta, out);
}